// Round 22
// baseline (766.146 us; speedup 1.0000x reference)
//
#include <hip/hip_runtime.h>
#include <cmath>

// In-wave (wave0-only) LDS sync: orders all lanes' prior LDS ops.
#define WSYNC() asm volatile("s_waitcnt lgkmcnt(0)" ::: "memory")

// Full transpose of the used W1 rows: w1tF[m][n'] = W1[128+n'][m].
__global__ void transpose_w1(const float* __restrict__ W1g, float* __restrict__ w1t) {
    int idx = blockIdx.x * 256 + threadIdx.x;
    if (idx < 512*512) {
        int m = idx >> 9;
        int p = idx & 511;
        w1t[idx] = W1g[(size_t)(128+p)*512 + m];
    }
}

// One workgroup (512 threads) per sample. Based on R21 (absmax 4096, 638us).
// Change: {hd0, zd1} run in 2 groups of 8 columns (hd0 8-wide via the
// validated e0/e1 float4 pattern; zd1 = ONE w1t sweep feeding 8 ascending
// chains) -> W1 zd1-sweeps 4 -> 2 (-19% L2 traffic). Everything downstream
// runs verbatim R21 per 4-column half reading zd1a[h*4+jj]. tmpa+pool merged
// into one arena (same bytes) so the 8-wide hd0a costs no extra LDS; only
// zd1a grows (+8KB) -> ~48.6KB, still 3 blocks/CU.
__global__ __launch_bounds__(512, 6)
void leql_f32_kernel(const float* __restrict__ x,
                     const float* __restrict__ W0g, const float* __restrict__ b0g,
                     const float* __restrict__ W1g, const float* __restrict__ b1g,
                     const float* __restrict__ Wog, const float* __restrict__ bog,
                     const float* __restrict__ w1t,
                     float* __restrict__ out, int B)
{
    __shared__ float uf[32];
    __shared__ float WoS[1024];
    __shared__ float z0f[512], z1f[512];
    __shared__ float s0f[256], c0f[256], s1f[256], c1f[256];
    __shared__ float whatf[384];
    __shared__ float v0f[384];
    __shared__ float zd1a[8][512];
    __shared__ float Hf[32][17];
    __shared__ float yvf[2];
    __shared__ float ydS[2][4];
    __shared__ __align__(16) float arena[3584];  // tmpa[4][512] | hd0a[8][384] | vd0a | solve
    __shared__ int pivS;

    float (*tmpa)[512] = reinterpret_cast<float(*)[512]>(arena);          // [4][512]
    float (*hd0a)[384] = reinterpret_cast<float(*)[384]>(arena);          // [8][384] (tmpa dead)
    float (*vd0a)[384] = reinterpret_cast<float(*)[384]>(arena + 2048);   // [4][384]
    float (*Af)[33]    = reinterpret_cast<float(*)[33]>(arena);           // 528 floats (tmpa dead)
    float* rf   = arena + 528;   // [16]
    float* qdo  = arena + 544;   // [16]
    float* wkc  = arena + 560;   // [16]
    int*   ipiv = reinterpret_cast<int*>(arena + 576);  // [16]

    const int t = threadIdx.x;
    const int s = blockIdx.x;

    if (t < 32) uf[t] = x[s*32 + t];
    WoS[t] = Wog[t]; WoS[512+t] = Wog[512+t];
    __syncthreads();

    // ---- forward ----
    {
        const float* wr = &W0g[(128+t)*32];
        float acc = 0.0f;
        for (int c = 0; c < 32; ++c) acc = fmaf(wr[c], uf[c], acc);
        z0f[t] = __fadd_rn(acc, b0g[128+t]);
    }
    __syncthreads();
    if (t < 256) { s0f[t] = sinf(z0f[t]); c0f[t] = cosf(z0f[t]); }
    __syncthreads();
    if (t < 128)      tmpa[0][t] = 1.0f;                          // h0
    else if (t < 256) tmpa[0][t] = s0f[t-128];
    else if (t < 384) tmpa[0][t] = c0f[t-128];
    else              tmpa[0][t] = __fmul_rn(z0f[t-128], z0f[t]);
    __syncthreads();
    {
        float acc = 0.0f;
        if (w1t) {
            const float* wt = &w1t[t];
            for (int m = 0; m < 512; ++m)
                acc = fmaf(wt[(size_t)m*512], tmpa[0][m], acc);
        } else {
            const float* wr = &W1g[(size_t)(128+t)*512];
            for (int m = 0; m < 512; m += 4) {
                const float4 w = *(const float4*)(wr + m);
                acc = fmaf(w.x, tmpa[0][m+0], acc);
                acc = fmaf(w.y, tmpa[0][m+1], acc);
                acc = fmaf(w.z, tmpa[0][m+2], acc);
                acc = fmaf(w.w, tmpa[0][m+3], acc);
            }
        }
        z1f[t] = __fadd_rn(acc, b1g[128+t]);
    }
    __syncthreads();
    if (t < 256) { s1f[t] = sinf(z1f[t]); c1f[t] = cosf(z1f[t]); }
    __syncthreads();
    if (t < 128)      tmpa[0][t] = 1.0f;                          // h1
    else if (t < 256) tmpa[0][t] = s1f[t-128];
    else if (t < 384) tmpa[0][t] = c1f[t-128];
    else              tmpa[0][t] = __fmul_rn(z1f[t-128], z1f[t]);
    __syncthreads();
    if (t < 2) {
        float acc = 0.0f;
        for (int n = 0; n < 512; ++n) acc = fmaf(WoS[t*512 + n], tmpa[0][n], acc);
        yvf[t] = __fadd_rn(acc, bog[t]);
    }
    __syncthreads();

    const float y1 = yvf[0], y2 = yvf[1];

    // theta-gate early exit (bit-exact: reference where() zeroes jcob/h1/h2)
    if (!(y2 > 0.5f)) {
        if (t < 16)  out[s*16 + t] = 0.0f;
        if (t == 16) out[(size_t)B*16 + s] = 0.0f;
        if (t == 17) out[(size_t)B*17 + s] = y2;
        return;
    }

    const float y2sq = __fmul_rn(y2, y2);
    const float r2 = 1.0f / y2sq;                       // integer_pow(y2,-2)
    const float r3 = 1.0f / __fmul_rn(y2sq, y2);        // integer_pow(y2,-3)
    const float sd1f = 1.0f / y2;                       // div VJP wrt numerator
    const float sd2f = __fmul_rn(-y1, r2);              // mul(mul(neg(ct),y1),y2^-2)

    // ---- base reverse pass ----
    if (t < 384) {
        float acc = fmaf(WoS[128+t], sd1f, 0.0f);
        whatf[t] = fmaf(WoS[512+128+t], sd2f, acc);
    }
    __syncthreads();
    {
        float v;
        if (t < 128)      v =  __fmul_rn(whatf[t],     c1f[t]);
        else if (t < 256) v = -__fmul_rn(whatf[t],     s1f[t]);
        else if (t < 384) v =  __fmul_rn(whatf[t],     z1f[t+128]);
        else              v =  __fmul_rn(whatf[t-128], z1f[t-128]);
        tmpa[0][t] = v;
    }
    __syncthreads();
    if (t < 384) {
        const float* wc = &W1g[(size_t)128*512 + 128 + t];
        float acc = 0.0f;
        for (int p = 0; p < 512; ++p) acc = fmaf(tmpa[0][p], wc[(size_t)p*512], acc);
        v0f[t] = acc;
    }
    __syncthreads();
    {
        float v;
        if (t < 128)      v =  __fmul_rn(v0f[t],     c0f[t]);
        else if (t < 256) v = -__fmul_rn(v0f[t],     s0f[t]);
        else if (t < 384) v =  __fmul_rn(v0f[t],     z0f[t+128]);
        else              v =  __fmul_rn(v0f[t-128], z0f[t-128]);
        tmpa[0][t] = v;
    }
    __syncthreads();
    if (t < 32) {
        float acc = 0.0f;
        for (int p = 0; p < 512; ++p) acc = fmaf(tmpa[0][p], W0g[(128+p)*32 + t], acc);
        Hf[t][16] = acc;
    }
    __syncthreads();

    // ---- 16 tangent passes: 2 outer groups of 8 columns ----
    for (int g2 = 0; g2 < 2; ++g2) {
        const int cj0 = 16 + g2*8;

        // hd0 for 8 columns (arena = hd0a; tmpa dead here). Per-column
        // expressions verbatim; e0/e1 float4 pattern validated in R7/R8.
        if (t < 384) {
            if (t < 128) {
                const float4 e0 = *(const float4*)&W0g[(128+t)*32 + cj0];
                const float4 e1 = *(const float4*)&W0g[(128+t)*32 + cj0 + 4];
                const float cth = c0f[t];
                hd0a[0][t] = __fmul_rn(cth, e0.x);
                hd0a[1][t] = __fmul_rn(cth, e0.y);
                hd0a[2][t] = __fmul_rn(cth, e0.z);
                hd0a[3][t] = __fmul_rn(cth, e0.w);
                hd0a[4][t] = __fmul_rn(cth, e1.x);
                hd0a[5][t] = __fmul_rn(cth, e1.y);
                hd0a[6][t] = __fmul_rn(cth, e1.z);
                hd0a[7][t] = __fmul_rn(cth, e1.w);
            } else if (t < 256) {
                const float4 e0 = *(const float4*)&W0g[(128+t)*32 + cj0];
                const float4 e1 = *(const float4*)&W0g[(128+t)*32 + cj0 + 4];
                const float sth = s0f[t];
                hd0a[0][t] = -__fmul_rn(sth, e0.x);
                hd0a[1][t] = -__fmul_rn(sth, e0.y);
                hd0a[2][t] = -__fmul_rn(sth, e0.z);
                hd0a[3][t] = -__fmul_rn(sth, e0.w);
                hd0a[4][t] = -__fmul_rn(sth, e1.x);
                hd0a[5][t] = -__fmul_rn(sth, e1.y);
                hd0a[6][t] = -__fmul_rn(sth, e1.z);
                hd0a[7][t] = -__fmul_rn(sth, e1.w);
            } else {
                const int i = t - 256;
                const float4 p0 = *(const float4*)&W0g[(384+i)*32 + cj0];
                const float4 p1 = *(const float4*)&W0g[(384+i)*32 + cj0 + 4];
                const float4 q0 = *(const float4*)&W0g[(512+i)*32 + cj0];
                const float4 q1 = *(const float4*)&W0g[(512+i)*32 + cj0 + 4];
                const float za = z0f[384+i], zb = z0f[256+i];
                hd0a[0][t] = __fadd_rn(__fmul_rn(p0.x, za), __fmul_rn(zb, q0.x));
                hd0a[1][t] = __fadd_rn(__fmul_rn(p0.y, za), __fmul_rn(zb, q0.y));
                hd0a[2][t] = __fadd_rn(__fmul_rn(p0.z, za), __fmul_rn(zb, q0.z));
                hd0a[3][t] = __fadd_rn(__fmul_rn(p0.w, za), __fmul_rn(zb, q0.w));
                hd0a[4][t] = __fadd_rn(__fmul_rn(p1.x, za), __fmul_rn(zb, q1.x));
                hd0a[5][t] = __fadd_rn(__fmul_rn(p1.y, za), __fmul_rn(zb, q1.y));
                hd0a[6][t] = __fadd_rn(__fmul_rn(p1.z, za), __fmul_rn(zb, q1.z));
                hd0a[7][t] = __fadd_rn(__fmul_rn(p1.w, za), __fmul_rn(zb, q1.w));
            }
        }
        __syncthreads();

        // zd1 for 8 columns: ONE coalesced w1t sweep, 8 ascending chains
        {
            float a0=0.0f, a1=0.0f, a2=0.0f, a3=0.0f;
            float a4=0.0f, a5=0.0f, a6=0.0f, a7=0.0f;
            if (w1t) {
                const float* wt = &w1t[(size_t)128*512 + t];
                for (int m = 0; m < 384; ++m) {
                    const float w = wt[(size_t)m*512];
                    a0 = fmaf(w, hd0a[0][m], a0);
                    a1 = fmaf(w, hd0a[1][m], a1);
                    a2 = fmaf(w, hd0a[2][m], a2);
                    a3 = fmaf(w, hd0a[3][m], a3);
                    a4 = fmaf(w, hd0a[4][m], a4);
                    a5 = fmaf(w, hd0a[5][m], a5);
                    a6 = fmaf(w, hd0a[6][m], a6);
                    a7 = fmaf(w, hd0a[7][m], a7);
                }
            } else {
                const float* wr = &W1g[(size_t)(128+t)*512 + 128];
                for (int m = 0; m < 384; ++m) {
                    const float w = wr[m];
                    a0 = fmaf(w, hd0a[0][m], a0);
                    a1 = fmaf(w, hd0a[1][m], a1);
                    a2 = fmaf(w, hd0a[2][m], a2);
                    a3 = fmaf(w, hd0a[3][m], a3);
                    a4 = fmaf(w, hd0a[4][m], a4);
                    a5 = fmaf(w, hd0a[5][m], a5);
                    a6 = fmaf(w, hd0a[6][m], a6);
                    a7 = fmaf(w, hd0a[7][m], a7);
                }
            }
            zd1a[0][t]=a0; zd1a[1][t]=a1; zd1a[2][t]=a2; zd1a[3][t]=a3;
            zd1a[4][t]=a4; zd1a[5][t]=a5; zd1a[6][t]=a6; zd1a[7][t]=a7;
        }
        __syncthreads();                 // hd0a dead from here; arena -> tmpa

        // ---- inner: 2 halves of 4 columns, verbatim R21 ----
        for (int h = 0; h < 2; ++h) {
            const int q0 = h*4;          // zd1a column base for this half

            // h1d for 4 jj -> tmpa[jj][t] (expressions verbatim; zeros stored)
            for (int jj = 0; jj < 4; ++jj) {
                const float* zd1f = zd1a[q0 + jj];
                float v;
                if (t < 128)      v = 0.0f;
                else if (t < 256) v =  __fmul_rn(c1f[t-128], zd1f[t-128]);
                else if (t < 384) v = -__fmul_rn(s1f[t-128], zd1f[t-128]);
                else              v = __fadd_rn(__fmul_rn(zd1f[t-128], z1f[t]),
                                                __fmul_rn(z1f[t-128], zd1f[t]));
                tmpa[jj][t] = v;
            }
            __syncthreads();

            // ydf: 8 concurrent chains (2m x 4jj), full ascending 0..511 order
            if (t < 8) {
                const int m = t & 1, jj = t >> 1;
                const float* hp = tmpa[jj];
                float acc = 0.0f;
                for (int n = 0; n < 512; ++n) acc = fmaf(WoS[m*512 + n], hp[n], acc);
                ydS[m][jj] = acc;
            }
            __syncthreads();

            // vdot1 per jj (champion form) -> tmpa[jj]; ONE barrier after
            for (int jj = 0; jj < 4; ++jj) {
                const float* zd1f = zd1a[q0 + jj];
                {
                    float yd1 = ydS[0][jj], yd2 = ydS[1][jj];
                    float sdot1 = __fmul_rn(-yd2, r2);
                    float dr2 = __fmul_rn(__fmul_rn(yd2, -2.0f), r3);
                    float sdot2 = __fadd_rn(__fmul_rn(-yd1, r2), __fmul_rn(-y1, dr2));
                    int n = (t < 384) ? (128 + t) : t;
                    float wd = fmaf(WoS[512+n], sdot2, fmaf(WoS[n], sdot1, 0.0f));
                    float v;
                    if (t < 128) {
                        float dcs = __fmul_rn(zd1f[t], -s1f[t]);
                        v = __fadd_rn(__fmul_rn(wd, c1f[t]), __fmul_rn(whatf[t], dcs));
                    } else if (t < 256) {
                        float dsn = __fmul_rn(zd1f[t], c1f[t]);
                        v = __fadd_rn(__fmul_rn(wd, -s1f[t]), __fmul_rn(whatf[t], -dsn));
                    } else if (t < 384) {
                        v = __fadd_rn(__fmul_rn(wd, z1f[t+128]),
                                      __fmul_rn(whatf[t], zd1f[t+128]));
                    } else {
                        v = __fadd_rn(__fmul_rn(wd, z1f[t-128]),
                                      __fmul_rn(whatf[t-128], zd1f[t-128]));
                    }
                    tmpa[jj][t] = v;
                }
            }
            __syncthreads();

            // vd0: ONE coalesced W1-column sweep feeds 4 ascending chains
            if (t < 384) {
                const float* wc = &W1g[(size_t)128*512 + 128 + t];
                float a0=0.0f, a1=0.0f, a2=0.0f, a3=0.0f;
                for (int p = 0; p < 512; ++p) {
                    const float w = wc[(size_t)p*512];
                    a0 = fmaf(tmpa[0][p], w, a0);
                    a1 = fmaf(tmpa[1][p], w, a1);
                    a2 = fmaf(tmpa[2][p], w, a2);
                    a3 = fmaf(tmpa[3][p], w, a3);
                }
                vd0a[0][t]=a0; vd0a[1][t]=a1; vd0a[2][t]=a2; vd0a[3][t]=a3;
            }
            __syncthreads();

            // dzdot0 per jj (champion form) -> tmpa[jj]; ONE barrier after
            for (int jj = 0; jj < 4; ++jj) {
                const int cj = 16 + g2*8 + h*4 + jj;
                const float* vd0f = vd0a[jj];
                {
                    float v;
                    if (t < 128) {
                        float e = W0g[(128+t)*32 + cj];
                        float dcs = __fmul_rn(e, -s0f[t]);
                        v = __fadd_rn(__fmul_rn(vd0f[t], c0f[t]), __fmul_rn(v0f[t], dcs));
                    } else if (t < 256) {
                        float e = W0g[(128+t)*32 + cj];
                        float dsn = __fmul_rn(e, c0f[t]);
                        v = __fadd_rn(__fmul_rn(vd0f[t], -s0f[t]), __fmul_rn(v0f[t], -dsn));
                    } else if (t < 384) {
                        float eb = W0g[(256+t)*32 + cj];
                        v = __fadd_rn(__fmul_rn(vd0f[t], z0f[t+128]), __fmul_rn(v0f[t], eb));
                    } else {
                        float ea = W0g[t*32 + cj];
                        v = __fadd_rn(__fmul_rn(vd0f[t-128], z0f[t-128]), __fmul_rn(v0f[t-128], ea));
                    }
                    tmpa[jj][t] = v;
                }
            }
            __syncthreads();

            // Hf BATCHED: ONE phase, 128 threads (32 i x 4 jj), chains verbatim
            if (t < 128) {
                const int i = t & 31, jj = t >> 5;
                const float* tp = tmpa[jj];
                float acc = 0.0f;
                for (int p = 0; p < 512; ++p)
                    acc = fmaf(tp[p], W0g[(128+p)*32 + i], acc);
                Hf[i][g2*8 + h*4 + jj] = acc;
            }
            __syncthreads();
        }
    }

    // ---- A = h1 + eps I; rhs = jcob - h2@q  (arena -> solve arrays) ----
    if (t < 256) {
        int i = t >> 4, jj = t & 15;
        Af[i][jj] = (i == jj) ? __fadd_rn(Hf[16+i][jj], 1.0e-3f) : Hf[16+i][jj];
    }
    if (t >= 256 && t < 272) {
        int i = t - 256;
        float dd = 0.0f;
        for (int jj = 0; jj < 16; ++jj) dd = fmaf(Hf[i][jj], uf[jj], dd);
        rf[i] = __fsub_rn(Hf[i][16], dd);
    }
    __syncthreads();

    // ---- solve: entirely in wave 0, lockstep-synced (validated R18) ----
    if (t < 64) {
        // sgetf2
        for (int j = 0; j < 16; ++j) {
            if (t == 0) {
                int p = j; float best = fabsf(Af[j][j]);
                for (int r = j+1; r < 16; ++r) {
                    float v = fabsf(Af[r][j]);
                    if (v > best) { best = v; p = r; }
                }
                ipiv[j] = p; pivS = p;
            }
            WSYNC();
            const int piv = pivS;
            if (piv != j && t < 16) {
                float tv = Af[j][t]; Af[j][t] = Af[piv][t]; Af[piv][t] = tv;
            }
            WSYNC();
            const float recip = 1.0f / Af[j][j];
            if (t > j && t < 16) Af[t][j] = __fmul_rn(Af[t][j], recip);
            WSYNC();
            #pragma unroll
            for (int e = 0; e < 4; ++e) {
                const int idx = t + 64*e;
                const int i = idx >> 4, k = idx & 15;
                if (i > j && k > j) Af[i][k] = fmaf(-Af[i][j], Af[j][k], Af[i][k]);
            }
            WSYNC();
        }
        // sgetri: strti2 lane-parallel over i
        for (int j = 0; j < 16; ++j) {
            const float ajj_inv = 1.0f / Af[j][j];
            if (t == 0) Af[j][j] = ajj_inv;
            const float ajj = -ajj_inv;
            WSYNC();
            for (int j2 = 0; j2 < j; ++j2) {
                const float temp = Af[j2][j];
                if (temp != 0.0f && t < j2) Af[t][j] = fmaf(temp, Af[t][j2], Af[t][j]);
                if (t == 0) Af[j2][j] = __fmul_rn(temp, Af[j2][j2]);
                WSYNC();
            }
            if (t < j) Af[t][j] = __fmul_rn(Af[t][j], ajj);
            WSYNC();
        }
        // descending-j sweep
        for (int j = 15; j >= 0; --j) {
            if (t > j && t < 16) { wkc[t] = Af[t][j]; Af[t][j] = 0.0f; }
            WSYNC();
            if (t < 16) {
                float acc = Af[t][j];
                for (int k = j+1; k < 16; ++k) acc = fmaf(-wkc[k], Af[t][k], acc);
                Af[t][j] = acc;
            }
            WSYNC();
        }
        // reverse column pivots (per-lane row-local)
        if (t < 16) {
            for (int j = 15; j >= 0; --j) {
                const int jp = ipiv[j];
                if (jp != j) { float tv = Af[t][j]; Af[t][j] = Af[t][jp]; Af[t][jp] = tv; }
            }
        }
        WSYNC();
        // qdd = inv @ rhs
        if (t < 16) {
            float acc = 0.0f;
            #pragma unroll
            for (int jj = 0; jj < 16; ++jj) acc = fmaf(Af[t][jj], rf[jj], acc);
            qdo[t] = acc;
        }
        WSYNC();
        // ---- outputs (gate is true on this path) ----
        if (t < 16)  out[s*16 + t] = qdo[t];
        if (t == 16) out[(size_t)B*16 + s] = y1 / y2;
        if (t == 17) out[(size_t)B*17 + s] = y2;
    }
}

extern "C" void kernel_launch(void* const* d_in, const int* in_sizes, int n_in,
                              void* d_out, int out_size, void* d_ws, size_t ws_size,
                              hipStream_t stream) {
    (void)n_in; (void)out_size;
    const float* x  = (const float*)d_in[0];
    const float* W0 = (const float*)d_in[1];
    const float* b0 = (const float*)d_in[2];
    const float* W1 = (const float*)d_in[3];
    const float* b1 = (const float*)d_in[4];
    const float* Wo = (const float*)d_in[5];
    const float* bo = (const float*)d_in[6];
    const int B = in_sizes[0] / 32;
    const size_t need = (size_t)512 * 512 * sizeof(float);
    float* w1t = (d_ws != nullptr && ws_size >= need) ? (float*)d_ws : nullptr;
    if (w1t) {
        hipLaunchKernelGGL(transpose_w1, dim3((512*512 + 255)/256), dim3(256), 0, stream,
                           W1, w1t);
    }
    hipLaunchKernelGGL(leql_f32_kernel, dim3(B), dim3(512), 0, stream,
                       x, W0, b0, W1, b1, Wo, bo, w1t, (float*)d_out, B);
}

// Round 23
// 638.072 us; speedup vs baseline: 1.2007x; 1.2007x over previous
//
#include <hip/hip_runtime.h>
#include <cmath>

// In-wave (wave0-only) LDS sync: orders all lanes' prior LDS ops.
#define WSYNC() asm volatile("s_waitcnt lgkmcnt(0)" ::: "memory")

// Full transpose of the used W1 rows: w1tF[m][n'] = W1[128+n'][m].
__global__ void transpose_w1(const float* __restrict__ W1g, float* __restrict__ w1t) {
    int idx = blockIdx.x * 256 + threadIdx.x;
    if (idx < 512*512) {
        int m = idx >> 9;
        int p = idx & 511;
        w1t[idx] = W1g[(size_t)(128+p)*512 + m];
    }
}

// FINAL: byte-for-byte the R21 champion (absmax 4096, 638.6us; 8.6x session
// start). Stack: theta-gate early exit; w1t-coalesced z1/zd1 sweeps;
// hd0/zd1/vd0/h1d 4-col batching; 8-thread ydf; Hf-batch; merged-barrier
// vdot1/dzdot0; LDS pool aliasing (40448B); wave0 WSYNC solve; (512,6).
// Known dead ends: vdot1/dzdot0 cross-jj batching (1-2 bf16-ulp codegen
// shifts, R9/R12/R16); waves_per_eu=8 (forced 32-VGPR spill, R4/R14);
// 8-wide zd1 (scratch spill, R22: WRITE 9->33MB, 638->766us).
__global__ __launch_bounds__(512, 6)
void leql_f32_kernel(const float* __restrict__ x,
                     const float* __restrict__ W0g, const float* __restrict__ b0g,
                     const float* __restrict__ W1g, const float* __restrict__ b1g,
                     const float* __restrict__ Wog, const float* __restrict__ bog,
                     const float* __restrict__ w1t,
                     float* __restrict__ out, int B)
{
    __shared__ float uf[32];
    __shared__ float WoS[1024];
    __shared__ float z0f[512], z1f[512];
    __shared__ float s0f[256], c0f[256], s1f[256], c1f[256];
    __shared__ float whatf[384];
    __shared__ float v0f[384];
    __shared__ float zd1a[4][512];
    __shared__ float tmpa[4][512];       // tmpa[0] doubles as h0/h1/base scratch
    __shared__ float Hf[32][17];
    __shared__ float yvf[2];
    __shared__ float ydS[2][4];
    __shared__ __align__(16) float pool[1536];   // hd0a -> vd0a -> solve
    __shared__ int pivS;

    float (*hd0a)[384] = reinterpret_cast<float(*)[384]>(pool);
    float (*vd0a)[384] = reinterpret_cast<float(*)[384]>(pool);
    float (*Af)[33]    = reinterpret_cast<float(*)[33]>(pool);   // 528 floats
    float* rf   = pool + 528;   // [16]
    float* qdo  = pool + 544;   // [16]
    float* wkc  = pool + 560;   // [16]
    int*   ipiv = reinterpret_cast<int*>(pool + 576);  // [16]

    const int t = threadIdx.x;
    const int s = blockIdx.x;

    if (t < 32) uf[t] = x[s*32 + t];
    WoS[t] = Wog[t]; WoS[512+t] = Wog[512+t];
    __syncthreads();

    // ---- forward ----
    {
        const float* wr = &W0g[(128+t)*32];
        float acc = 0.0f;
        for (int c = 0; c < 32; ++c) acc = fmaf(wr[c], uf[c], acc);
        z0f[t] = __fadd_rn(acc, b0g[128+t]);
    }
    __syncthreads();
    if (t < 256) { s0f[t] = sinf(z0f[t]); c0f[t] = cosf(z0f[t]); }
    __syncthreads();
    if (t < 128)      tmpa[0][t] = 1.0f;                          // h0
    else if (t < 256) tmpa[0][t] = s0f[t-128];
    else if (t < 384) tmpa[0][t] = c0f[t-128];
    else              tmpa[0][t] = __fmul_rn(z0f[t-128], z0f[t]);
    __syncthreads();
    {
        float acc = 0.0f;
        if (w1t) {
            const float* wt = &w1t[t];
            for (int m = 0; m < 512; ++m)
                acc = fmaf(wt[(size_t)m*512], tmpa[0][m], acc);
        } else {
            const float* wr = &W1g[(size_t)(128+t)*512];
            for (int m = 0; m < 512; m += 4) {
                const float4 w = *(const float4*)(wr + m);
                acc = fmaf(w.x, tmpa[0][m+0], acc);
                acc = fmaf(w.y, tmpa[0][m+1], acc);
                acc = fmaf(w.z, tmpa[0][m+2], acc);
                acc = fmaf(w.w, tmpa[0][m+3], acc);
            }
        }
        z1f[t] = __fadd_rn(acc, b1g[128+t]);
    }
    __syncthreads();
    if (t < 256) { s1f[t] = sinf(z1f[t]); c1f[t] = cosf(z1f[t]); }
    __syncthreads();
    if (t < 128)      tmpa[0][t] = 1.0f;                          // h1
    else if (t < 256) tmpa[0][t] = s1f[t-128];
    else if (t < 384) tmpa[0][t] = c1f[t-128];
    else              tmpa[0][t] = __fmul_rn(z1f[t-128], z1f[t]);
    __syncthreads();
    if (t < 2) {
        float acc = 0.0f;
        for (int n = 0; n < 512; ++n) acc = fmaf(WoS[t*512 + n], tmpa[0][n], acc);
        yvf[t] = __fadd_rn(acc, bog[t]);
    }
    __syncthreads();

    const float y1 = yvf[0], y2 = yvf[1];

    // theta-gate early exit (bit-exact: reference where() zeroes jcob/h1/h2)
    if (!(y2 > 0.5f)) {
        if (t < 16)  out[s*16 + t] = 0.0f;
        if (t == 16) out[(size_t)B*16 + s] = 0.0f;
        if (t == 17) out[(size_t)B*17 + s] = y2;
        return;
    }

    const float y2sq = __fmul_rn(y2, y2);
    const float r2 = 1.0f / y2sq;                       // integer_pow(y2,-2)
    const float r3 = 1.0f / __fmul_rn(y2sq, y2);        // integer_pow(y2,-3)
    const float sd1f = 1.0f / y2;                       // div VJP wrt numerator
    const float sd2f = __fmul_rn(-y1, r2);              // mul(mul(neg(ct),y1),y2^-2)

    // ---- base reverse pass ----
    if (t < 384) {
        float acc = fmaf(WoS[128+t], sd1f, 0.0f);
        whatf[t] = fmaf(WoS[512+128+t], sd2f, acc);
    }
    __syncthreads();
    {
        float v;
        if (t < 128)      v =  __fmul_rn(whatf[t],     c1f[t]);
        else if (t < 256) v = -__fmul_rn(whatf[t],     s1f[t]);
        else if (t < 384) v =  __fmul_rn(whatf[t],     z1f[t+128]);
        else              v =  __fmul_rn(whatf[t-128], z1f[t-128]);
        tmpa[0][t] = v;
    }
    __syncthreads();
    if (t < 384) {
        const float* wc = &W1g[(size_t)128*512 + 128 + t];
        float acc = 0.0f;
        for (int p = 0; p < 512; ++p) acc = fmaf(tmpa[0][p], wc[(size_t)p*512], acc);
        v0f[t] = acc;
    }
    __syncthreads();
    {
        float v;
        if (t < 128)      v =  __fmul_rn(v0f[t],     c0f[t]);
        else if (t < 256) v = -__fmul_rn(v0f[t],     s0f[t]);
        else if (t < 384) v =  __fmul_rn(v0f[t],     z0f[t+128]);
        else              v =  __fmul_rn(v0f[t-128], z0f[t-128]);
        tmpa[0][t] = v;
    }
    __syncthreads();
    if (t < 32) {
        float acc = 0.0f;
        for (int p = 0; p < 512; ++p) acc = fmaf(tmpa[0][p], W0g[(128+p)*32 + t], acc);
        Hf[t][16] = acc;
    }
    __syncthreads();

    // ---- 16 tangent passes: 4 groups of 4 ----
    for (int g = 0; g < 4; ++g) {
        const int cj0 = 16 + g*4;

        // hd0 for 4 columns (pool = hd0a)
        if (t < 384) {
            if (t < 128) {
                const float4 e = *(const float4*)&W0g[(128+t)*32 + cj0];
                const float cth = c0f[t];
                hd0a[0][t] = __fmul_rn(cth, e.x);
                hd0a[1][t] = __fmul_rn(cth, e.y);
                hd0a[2][t] = __fmul_rn(cth, e.z);
                hd0a[3][t] = __fmul_rn(cth, e.w);
            } else if (t < 256) {
                const float4 e = *(const float4*)&W0g[(128+t)*32 + cj0];
                const float sth = s0f[t];
                hd0a[0][t] = -__fmul_rn(sth, e.x);
                hd0a[1][t] = -__fmul_rn(sth, e.y);
                hd0a[2][t] = -__fmul_rn(sth, e.z);
                hd0a[3][t] = -__fmul_rn(sth, e.w);
            } else {
                const int i = t - 256;
                const float4 p4 = *(const float4*)&W0g[(384+i)*32 + cj0];
                const float4 q4 = *(const float4*)&W0g[(512+i)*32 + cj0];
                const float za = z0f[384+i], zb = z0f[256+i];
                hd0a[0][t] = __fadd_rn(__fmul_rn(p4.x, za), __fmul_rn(zb, q4.x));
                hd0a[1][t] = __fadd_rn(__fmul_rn(p4.y, za), __fmul_rn(zb, q4.y));
                hd0a[2][t] = __fadd_rn(__fmul_rn(p4.z, za), __fmul_rn(zb, q4.z));
                hd0a[3][t] = __fadd_rn(__fmul_rn(p4.w, za), __fmul_rn(zb, q4.w));
            }
        }
        __syncthreads();

        // zd1 for 4 columns (one coalesced w1t sweep, 4 chains)
        {
            float a0=0.0f, a1=0.0f, a2=0.0f, a3=0.0f;
            if (w1t) {
                const float* wt = &w1t[(size_t)128*512 + t];
                for (int m = 0; m < 384; ++m) {
                    const float w = wt[(size_t)m*512];
                    a0 = fmaf(w, hd0a[0][m], a0);
                    a1 = fmaf(w, hd0a[1][m], a1);
                    a2 = fmaf(w, hd0a[2][m], a2);
                    a3 = fmaf(w, hd0a[3][m], a3);
                }
            } else {
                const float* wr = &W1g[(size_t)(128+t)*512 + 128];
                for (int m = 0; m < 384; m += 4) {
                    const float4 w  = *(const float4*)(wr + m);
                    const float4 h0 = *(const float4*)&hd0a[0][m];
                    const float4 h1 = *(const float4*)&hd0a[1][m];
                    const float4 h2 = *(const float4*)&hd0a[2][m];
                    const float4 h3 = *(const float4*)&hd0a[3][m];
                    a0 = fmaf(w.x, h0.x, a0); a0 = fmaf(w.y, h0.y, a0);
                    a0 = fmaf(w.z, h0.z, a0); a0 = fmaf(w.w, h0.w, a0);
                    a1 = fmaf(w.x, h1.x, a1); a1 = fmaf(w.y, h1.y, a1);
                    a1 = fmaf(w.z, h1.z, a1); a1 = fmaf(w.w, h1.w, a1);
                    a2 = fmaf(w.x, h2.x, a2); a2 = fmaf(w.y, h2.y, a2);
                    a2 = fmaf(w.z, h2.z, a2); a2 = fmaf(w.w, h2.w, a2);
                    a3 = fmaf(w.x, h3.x, a3); a3 = fmaf(w.y, h3.y, a3);
                    a3 = fmaf(w.z, h3.z, a3); a3 = fmaf(w.w, h3.w, a3);
                }
            }
            zd1a[0][t]=a0; zd1a[1][t]=a1; zd1a[2][t]=a2; zd1a[3][t]=a3;
        }
        __syncthreads();                 // hd0a dead from here

        // h1d for ALL 4 jj -> tmpa[jj][t] (expressions verbatim; zeros stored)
        for (int jj = 0; jj < 4; ++jj) {
            const float* zd1f = zd1a[jj];
            float v;
            if (t < 128)      v = 0.0f;
            else if (t < 256) v =  __fmul_rn(c1f[t-128], zd1f[t-128]);
            else if (t < 384) v = -__fmul_rn(s1f[t-128], zd1f[t-128]);
            else              v = __fadd_rn(__fmul_rn(zd1f[t-128], z1f[t]),
                                            __fmul_rn(z1f[t-128], zd1f[t]));
            tmpa[jj][t] = v;
        }
        __syncthreads();

        // ydf: 8 concurrent chains (2m x 4jj), full ascending 0..511 order
        if (t < 8) {
            const int m = t & 1, jj = t >> 1;
            const float* hp = tmpa[jj];
            float acc = 0.0f;
            for (int n = 0; n < 512; ++n) acc = fmaf(WoS[m*512 + n], hp[n], acc);
            ydS[m][jj] = acc;
        }
        __syncthreads();

        // vdot1 per jj (champion form) -> tmpa[jj]; ONE barrier after the loop
        for (int jj = 0; jj < 4; ++jj) {
            const float* zd1f = zd1a[jj];
            {
                float yd1 = ydS[0][jj], yd2 = ydS[1][jj];
                float sdot1 = __fmul_rn(-yd2, r2);
                float dr2 = __fmul_rn(__fmul_rn(yd2, -2.0f), r3);
                float sdot2 = __fadd_rn(__fmul_rn(-yd1, r2), __fmul_rn(-y1, dr2));
                int n = (t < 384) ? (128 + t) : t;
                float wd = fmaf(WoS[512+n], sdot2, fmaf(WoS[n], sdot1, 0.0f));
                float v;
                if (t < 128) {
                    float dcs = __fmul_rn(zd1f[t], -s1f[t]);
                    v = __fadd_rn(__fmul_rn(wd, c1f[t]), __fmul_rn(whatf[t], dcs));
                } else if (t < 256) {
                    float dsn = __fmul_rn(zd1f[t], c1f[t]);
                    v = __fadd_rn(__fmul_rn(wd, -s1f[t]), __fmul_rn(whatf[t], -dsn));
                } else if (t < 384) {
                    v = __fadd_rn(__fmul_rn(wd, z1f[t+128]),
                                  __fmul_rn(whatf[t], zd1f[t+128]));
                } else {
                    v = __fadd_rn(__fmul_rn(wd, z1f[t-128]),
                                  __fmul_rn(whatf[t-128], zd1f[t-128]));
                }
                tmpa[jj][t] = v;
            }
        }
        __syncthreads();

        // vd0: ONE coalesced W1-column sweep feeds 4 ascending chains
        if (t < 384) {
            const float* wc = &W1g[(size_t)128*512 + 128 + t];
            float a0=0.0f, a1=0.0f, a2=0.0f, a3=0.0f;
            for (int p = 0; p < 512; ++p) {
                const float w = wc[(size_t)p*512];
                a0 = fmaf(tmpa[0][p], w, a0);
                a1 = fmaf(tmpa[1][p], w, a1);
                a2 = fmaf(tmpa[2][p], w, a2);
                a3 = fmaf(tmpa[3][p], w, a3);
            }
            vd0a[0][t]=a0; vd0a[1][t]=a1; vd0a[2][t]=a2; vd0a[3][t]=a3;
        }
        __syncthreads();

        // dzdot0 per jj (champion form) -> tmpa[jj]; ONE barrier after the loop
        for (int jj = 0; jj < 4; ++jj) {
            const int cj = 16 + g*4 + jj;
            const float* vd0f = vd0a[jj];
            {
                float v;
                if (t < 128) {
                    float e = W0g[(128+t)*32 + cj];
                    float dcs = __fmul_rn(e, -s0f[t]);
                    v = __fadd_rn(__fmul_rn(vd0f[t], c0f[t]), __fmul_rn(v0f[t], dcs));
                } else if (t < 256) {
                    float e = W0g[(128+t)*32 + cj];
                    float dsn = __fmul_rn(e, c0f[t]);
                    v = __fadd_rn(__fmul_rn(vd0f[t], -s0f[t]), __fmul_rn(v0f[t], -dsn));
                } else if (t < 384) {
                    float eb = W0g[(256+t)*32 + cj];
                    v = __fadd_rn(__fmul_rn(vd0f[t], z0f[t+128]), __fmul_rn(v0f[t], eb));
                } else {
                    float ea = W0g[t*32 + cj];
                    v = __fadd_rn(__fmul_rn(vd0f[t-128], z0f[t-128]), __fmul_rn(v0f[t-128], ea));
                }
                tmpa[jj][t] = v;
            }
        }
        __syncthreads();

        // Hf BATCHED: ONE phase, 128 threads (32 i x 4 jj), chains verbatim
        if (t < 128) {
            const int i = t & 31, jj = t >> 5;
            const float* tp = tmpa[jj];
            float acc = 0.0f;
            for (int p = 0; p < 512; ++p)
                acc = fmaf(tp[p], W0g[(128+p)*32 + i], acc);
            Hf[i][g*4 + jj] = acc;
        }
        __syncthreads();                 // vd0a dead after this
    }

    // ---- A = h1 + eps I; rhs = jcob - h2@q  (pool -> solve arrays) ----
    if (t < 256) {
        int i = t >> 4, jj = t & 15;
        Af[i][jj] = (i == jj) ? __fadd_rn(Hf[16+i][jj], 1.0e-3f) : Hf[16+i][jj];
    }
    if (t >= 256 && t < 272) {
        int i = t - 256;
        float dd = 0.0f;
        for (int jj = 0; jj < 16; ++jj) dd = fmaf(Hf[i][jj], uf[jj], dd);
        rf[i] = __fsub_rn(Hf[i][16], dd);
    }
    __syncthreads();

    // ---- solve: entirely in wave 0, lockstep-synced (validated R18) ----
    if (t < 64) {
        // sgetf2
        for (int j = 0; j < 16; ++j) {
            if (t == 0) {
                int p = j; float best = fabsf(Af[j][j]);
                for (int r = j+1; r < 16; ++r) {
                    float v = fabsf(Af[r][j]);
                    if (v > best) { best = v; p = r; }
                }
                ipiv[j] = p; pivS = p;
            }
            WSYNC();
            const int piv = pivS;
            if (piv != j && t < 16) {
                float tv = Af[j][t]; Af[j][t] = Af[piv][t]; Af[piv][t] = tv;
            }
            WSYNC();
            const float recip = 1.0f / Af[j][j];
            if (t > j && t < 16) Af[t][j] = __fmul_rn(Af[t][j], recip);
            WSYNC();
            #pragma unroll
            for (int e = 0; e < 4; ++e) {
                const int idx = t + 64*e;
                const int i = idx >> 4, k = idx & 15;
                if (i > j && k > j) Af[i][k] = fmaf(-Af[i][j], Af[j][k], Af[i][k]);
            }
            WSYNC();
        }
        // sgetri: strti2 lane-parallel over i
        for (int j = 0; j < 16; ++j) {
            const float ajj_inv = 1.0f / Af[j][j];
            if (t == 0) Af[j][j] = ajj_inv;
            const float ajj = -ajj_inv;
            WSYNC();
            for (int j2 = 0; j2 < j; ++j2) {
                const float temp = Af[j2][j];
                if (temp != 0.0f && t < j2) Af[t][j] = fmaf(temp, Af[t][j2], Af[t][j]);
                if (t == 0) Af[j2][j] = __fmul_rn(temp, Af[j2][j2]);
                WSYNC();
            }
            if (t < j) Af[t][j] = __fmul_rn(Af[t][j], ajj);
            WSYNC();
        }
        // descending-j sweep
        for (int j = 15; j >= 0; --j) {
            if (t > j && t < 16) { wkc[t] = Af[t][j]; Af[t][j] = 0.0f; }
            WSYNC();
            if (t < 16) {
                float acc = Af[t][j];
                for (int k = j+1; k < 16; ++k) acc = fmaf(-wkc[k], Af[t][k], acc);
                Af[t][j] = acc;
            }
            WSYNC();
        }
        // reverse column pivots (per-lane row-local)
        if (t < 16) {
            for (int j = 15; j >= 0; --j) {
                const int jp = ipiv[j];
                if (jp != j) { float tv = Af[t][j]; Af[t][j] = Af[t][jp]; Af[t][jp] = tv; }
            }
        }
        WSYNC();
        // qdd = inv @ rhs
        if (t < 16) {
            float acc = 0.0f;
            #pragma unroll
            for (int jj = 0; jj < 16; ++jj) acc = fmaf(Af[t][jj], rf[jj], acc);
            qdo[t] = acc;
        }
        WSYNC();
        // ---- outputs (gate is true on this path) ----
        if (t < 16)  out[s*16 + t] = qdo[t];
        if (t == 16) out[(size_t)B*16 + s] = y1 / y2;
        if (t == 17) out[(size_t)B*17 + s] = y2;
    }
}

extern "C" void kernel_launch(void* const* d_in, const int* in_sizes, int n_in,
                              void* d_out, int out_size, void* d_ws, size_t ws_size,
                              hipStream_t stream) {
    (void)n_in; (void)out_size;
    const float* x  = (const float*)d_in[0];
    const float* W0 = (const float*)d_in[1];
    const float* b0 = (const float*)d_in[2];
    const float* W1 = (const float*)d_in[3];
    const float* b1 = (const float*)d_in[4];
    const float* Wo = (const float*)d_in[5];
    const float* bo = (const float*)d_in[6];
    const int B = in_sizes[0] / 32;
    const size_t need = (size_t)512 * 512 * sizeof(float);
    float* w1t = (d_ws != nullptr && ws_size >= need) ? (float*)d_ws : nullptr;
    if (w1t) {
        hipLaunchKernelGGL(transpose_w1, dim3((512*512 + 255)/256), dim3(256), 0, stream,
                           W1, w1t);
    }
    hipLaunchKernelGGL(leql_f32_kernel, dim3(B), dim3(512), 0, stream,
                       x, W0, b0, W1, b1, Wo, bo, w1t, (float*)d_out, B);
}